// Round 10
// baseline (371.124 us; speedup 1.0000x reference)
//
#include <hip/hip_runtime.h>
#include <hip/hip_bf16.h>

#define N_NODES 50000
#define E0      800000
#define ET      850000   // E0 + N_NODES self-loops
#define IN_F    128
#define HF      256
#define HID     64
#define NEG     0.2f
#define BN_EPSC 1e-5f
#define NSCAN_BLK 196    // ceil(50000/256)
#define NCHUNKS 37500    // 3 inst x 12500 node-chunks

typedef __attribute__((ext_vector_type(8))) short bh8;            // 8 bf16 (4 VGPRs)
typedef __attribute__((ext_vector_type(4))) float fl4;            // 4 f32 accum
typedef __attribute__((ext_vector_type(8))) unsigned short us8;   // 8 u16

__device__ __forceinline__ float lrelu(float x){ return x > 0.f ? x : NEG * x; }
__device__ __forceinline__ unsigned short f2b(float f){
  unsigned int x = __float_as_uint(f);
  unsigned int r = x + 0x7FFF + ((x >> 16) & 1);   // RNE
  return (unsigned short)(r >> 16);
}
__device__ __forceinline__ float b2f(unsigned short u){
  return __uint_as_float((unsigned int)u << 16);
}

// permutation within each 64-col head block: col' = blk + l15*4 + n holds true col blk + n*16 + l15
__device__ __forceinline__ int perm_true(int cp){
  int blk = cp & ~63, r = cp & 63;
  return blk + (r & 3) * 16 + (r >> 2);
}

// ---------------- prep: W->bf16, linW->bf16 (K-permuted), BN scale/shift + bias (permuted) ----------------
#define NW4 (3 * HF * IN_F / 4)     // 24576
#define NL4 (3 * HID * HF / 4)      // 12288
__global__ __launch_bounds__(256) void k_prep(const float* __restrict__ W, unsigned short* __restrict__ wb,
                                              const float* __restrict__ linW, unsigned short* __restrict__ lwb,
                                              const float* __restrict__ g, const float* __restrict__ b,
                                              const float* __restrict__ m, const float* __restrict__ v,
                                              const float* __restrict__ bias,
                                              float* __restrict__ scale, float* __restrict__ shiftv,
                                              float* __restrict__ bias_p){
  int idx = blockIdx.x * 256 + threadIdx.x;
  if (idx < NW4){
    float4 x = ((const float4*)W)[idx];
    ((ushort4*)wb)[idx] = make_ushort4(f2b(x.x), f2b(x.y), f2b(x.z), f2b(x.w));
  } else if (idx < NW4 + NL4){
    int j = idx - NW4;
    int j4 = j * 4;
    int irow = j4 >> 8;             // [0, 192): inst*64+row
    int cp = j4 & 255;              // 4-aligned -> l15 = (cp&63)>>2, n = 0..3
    int blk = cp & ~63, l15 = (cp & 63) >> 2;
    const float* src = linW + (size_t)irow * HF + blk + l15;
    ushort4 o = make_ushort4(f2b(src[0]), f2b(src[16]), f2b(src[32]), f2b(src[48]));
    ((ushort4*)lwb)[j] = o;
  } else if (idx < NW4 + NL4 + 3 * HF){
    int i = idx - NW4 - NL4;        // [0,768): inst*256 + col'
    int inst = i >> 8, cp = i & 255;
    int c = inst * HF + perm_true(cp);
    float s = g[c] * rsqrtf(v[c] + BN_EPSC);
    scale[i] = s;
    shiftv[i] = b[c] - m[c] * s;
  } else if (idx < NW4 + NL4 + 6 * HF){
    int i = idx - NW4 - NL4 - 3 * HF;
    int inst = i >> 8, cp = i & 255;
    bias_p[i] = bias[inst * HF + perm_true(cp)];
  }
}

// ---------------- CSR build ----------------
__global__ void k_hist(const int* __restrict__ ei, int* __restrict__ counts){
  int e = blockIdx.x * 256 + threadIdx.x;
  if (e >= ET) return;
  int d = (e < E0) ? ei[E0 + e] : (e - E0);
  atomicAdd(&counts[d], 1);
}

__global__ __launch_bounds__(256) void k_bsum(const int* __restrict__ counts, int* __restrict__ bsums){
  int b = blockIdx.x;
  int t = threadIdx.x;
  int idx = b * 256 + t;
  int v = (idx < N_NODES) ? counts[idx] : 0;
  for (int m = 1; m < 64; m <<= 1) v += __shfl_xor(v, m, 64);
  __shared__ int ws[4];
  int lane = t & 63, w = t >> 6;
  if (lane == 0) ws[w] = v;
  __syncthreads();
  if (t == 0) bsums[b] = ws[0] + ws[1] + ws[2] + ws[3];
}

// fused: per-block redundant scan of bsums (196 ints) + per-block exclusive scan -> row_ptr/cursor
__global__ __launch_bounds__(256) void k_sfinal(const int* __restrict__ counts,
                                                const int* __restrict__ bsums,
                                                int* __restrict__ row_ptr, int* __restrict__ cursor){
  __shared__ int bex[256];
  __shared__ int ws0[4];
  __shared__ int ws[4];
  int b = blockIdx.x, t = threadIdx.x;
  int lane = t & 63, w = t >> 6;
  {
    int v = (t < NSCAN_BLK) ? bsums[t] : 0;
    int incl = v;
    for (int m = 1; m < 64; m <<= 1){ int n = __shfl_up(incl, m, 64); if (lane >= m) incl += n; }
    if (lane == 63) ws0[w] = incl;
    __syncthreads();
    if (t == 0){ int r = 0; for (int j = 0; j < 4; ++j){ int x = ws0[j]; ws0[j] = r; r += x; } }
    __syncthreads();
    int excl = incl - v + ws0[w];
    bex[t] = excl;
    if (b == 0 && t == 255) row_ptr[N_NODES] = excl + v;   // total == ET
    __syncthreads();
  }
  int idx = b * 256 + t;
  int v = (idx < N_NODES) ? counts[idx] : 0;
  int incl = v;
  for (int m = 1; m < 64; m <<= 1){ int n = __shfl_up(incl, m, 64); if (lane >= m) incl += n; }
  if (lane == 63) ws[w] = incl;
  __syncthreads();
  if (t == 0){ int r = 0; for (int j = 0; j < 4; ++j){ int x = ws[j]; ws[j] = r; r += x; } }
  __syncthreads();
  int excl = incl - v + ws[w];
  int pos = bex[b] + excl;
  if (idx < N_NODES){ row_ptr[idx] = pos; cursor[idx] = pos; }
}

__global__ void k_scatter(const int* __restrict__ ei, int* __restrict__ cursor,
                          int* __restrict__ csr_src){
  int e = blockIdx.x * 256 + threadIdx.x;
  if (e >= ET) return;
  int s, d;
  if (e < E0){ s = ei[e]; d = ei[E0 + e]; } else { s = e - E0; d = s; }
  int pos = atomicAdd(&cursor[d], 1);
  csr_src[pos] = s;
}

// ---------------- GEMM1 fused (3 inst): M=32 tile, A+B LDS-staged, permuted bf16 write + alpha ----------------
// 4 waves; wave w == head w (cols 64w..64w+63).
__global__ __launch_bounds__(256) void k_gemm1f(const float* __restrict__ sppmi,
                                                const unsigned short* __restrict__ wb,
                                                const float* __restrict__ att_src,
                                                const float* __restrict__ att_dst,
                                                unsigned short* __restrict__ xwb,
                                                float* __restrict__ as3, float* __restrict__ ad3){
  __shared__ unsigned char Asm[32 * 256];    // 8KB
  __shared__ unsigned char Bsm[256 * 256];   // 64KB
  int tid = threadIdx.x;
  int bx = blockIdx.x;
  int inst = bx / 1563;
  int m0 = (bx % 1563) * 32;
  const float* x = sppmi + (size_t)inst * N_NODES * IN_F;
  const unsigned short* wbv = wb + (size_t)inst * HF * IN_F;
  const float* asrc = att_src + inst * HF;
  const float* adst = att_dst + inst * HF;
  float* as_ = as3 + (size_t)inst * N_NODES * 4;
  float* ad_ = ad3 + (size_t)inst * N_NODES * 4;
  unsigned short* xw = xwb + (size_t)inst * N_NODES * HF;

  // stage A with fused f32->bf16
  #pragma unroll
  for (int k = 0; k < 4; ++k){
    int c = k * 256 + tid;
    int row = c >> 5;
    int c4 = c & 31;
    int grow = m0 + row; if (grow >= N_NODES) grow = N_NODES - 1;
    float4 v = *(const float4*)&x[(size_t)grow * IN_F + c4 * 4];
    ushort4 o = make_ushort4(f2b(v.x), f2b(v.y), f2b(v.z), f2b(v.w));
    int colb = c4 * 8;
    int addr = row * 256 + ((colb & ~15) ^ ((row & 7) << 4)) + (colb & 15);
    *(ushort4*)(Asm + addr) = o;
  }
  // stage B
  #pragma unroll
  for (int k = 0; k < 16; ++k){
    int c = k * 256 + tid;
    int row = c >> 4;
    int colb = (c & 15) * 16;
    uint4 v = *(const uint4*)((const char*)wbv + (size_t)row * 256 + colb);
    *(uint4*)(Bsm + row * 256 + (colb ^ ((row & 7) << 4))) = v;
  }
  __syncthreads();

  int w = tid >> 6, lane = tid & 63;
  int l15 = lane & 15, l4 = lane >> 4;
  fl4 acc[2][4] = {};
  #pragma unroll
  for (int kk = 0; kk < 4; ++kk){
    bh8 af[2];
    #pragma unroll
    for (int m = 0; m < 2; ++m){
      int ar = m * 16 + l15;
      int ac = (kk * 64 + l4 * 16) ^ ((ar & 7) << 4);
      af[m] = *(const bh8*)(Asm + ar * 256 + ac);
    }
    bh8 bfv[4];
    #pragma unroll
    for (int n = 0; n < 4; ++n){
      int br = w * 64 + n * 16 + l15;
      int bc = (kk * 64 + l4 * 16) ^ ((br & 7) << 4);
      bfv[n] = *(const bh8*)(Bsm + br * 256 + bc);
    }
    #pragma unroll
    for (int m = 0; m < 2; ++m)
      #pragma unroll
      for (int n = 0; n < 4; ++n)
        acc[m][n] = __builtin_amdgcn_mfma_f32_16x16x32_bf16(af[m], bfv[n], acc[m][n], 0, 0, 0);
  }

  float asv[4], adv[4];
  #pragma unroll
  for (int n = 0; n < 4; ++n){
    int c = w * 64 + n * 16 + l15;
    asv[n] = asrc[c]; adv[n] = adst[c];
  }

  #pragma unroll
  for (int m = 0; m < 2; ++m){
    #pragma unroll
    for (int j = 0; j < 4; ++j){
      int grow = m0 + m * 16 + l4 * 4 + j;
      if (grow < N_NODES){
        // permuted bf16 write: 4 contiguous cols' at w*64 + l15*4 (8B store)
        ushort4 o4 = make_ushort4(f2b(acc[m][0][j]), f2b(acc[m][1][j]),
                                  f2b(acc[m][2][j]), f2b(acc[m][3][j]));
        *(ushort4*)(xw + (size_t)grow * HF + w * 64 + l15 * 4) = o4;
      }
      float ts = acc[m][0][j]*asv[0] + acc[m][1][j]*asv[1] + acc[m][2][j]*asv[2] + acc[m][3][j]*asv[3];
      float td = acc[m][0][j]*adv[0] + acc[m][1][j]*adv[1] + acc[m][2][j]*adv[2] + acc[m][3][j]*adv[3];
      #pragma unroll
      for (int mm = 1; mm < 16; mm <<= 1){ ts += __shfl_xor(ts, mm, 64); td += __shfl_xor(td, mm, 64); }
      if (l15 == 0 && grow < N_NODES){
        as_[grow * 4 + w] = ts;
        ad_[grow * 4 + w] = td;
      }
    }
  }
}

// ---------------- aggregation (3 inst, permuted bf16 rows): grid-stride, exp + LDS broadcast ----------------
// chunks = 37500; inst = c/12500; node = (c%12500)*4 + wave.
__global__ __launch_bounds__(256) void k_agg3(const unsigned short* __restrict__ xwb,
                     const float* __restrict__ as3, const float* __restrict__ ad3,
                     const int* __restrict__ row_ptr, const int* __restrict__ csr_src,
                     const float* __restrict__ bias_p, unsigned short* __restrict__ outb){
  __shared__ float eLds[4][4][65];
  __shared__ int   sLds[4][64];   // byte offsets (src * 512)
  int w = threadIdx.x >> 6;
  int lane = threadIdx.x & 63;
  int h = lane >> 4;
  int lb = lane * 8;

  for (int c = blockIdx.x; c < NCHUNKS; c += gridDim.x){
    int inst = c / 12500;
    int chunk = c - inst * 12500;
    int node = chunk * 4 + w;
    int row0 = row_ptr[node];
    int deg = row_ptr[node + 1] - row0;
    const float* as_ = as3 + (size_t)inst * N_NODES * 4;
    const float* ad_ = ad3 + (size_t)inst * N_NODES * 4;
    float4 ad4 = *(const float4*)&ad_[node * 4];
    float accx = 0.f, accy = 0.f, accz = 0.f, accw = 0.f;
    float sh;
    const char* xwp = (const char*)(xwb + (size_t)inst * N_NODES * HF);

    if (deg <= 64){
      int soff = 0; float e0 = 0.f, e1 = 0.f, e2 = 0.f, e3 = 0.f;
      if (lane < deg){
        int sreg = csr_src[row0 + lane];
        soff = sreg << 9;   // *512B
        float4 a4 = *(const float4*)&as_[sreg * 4];
        e0 = __expf(lrelu(a4.x + ad4.x));
        e1 = __expf(lrelu(a4.y + ad4.y));
        e2 = __expf(lrelu(a4.z + ad4.z));
        e3 = __expf(lrelu(a4.w + ad4.w));
      }
      sLds[w][lane] = soff;
      eLds[w][0][lane] = e0; eLds[w][1][lane] = e1;
      eLds[w][2][lane] = e2; eLds[w][3][lane] = e3;
      float s0 = e0, s1 = e1, s2 = e2, s3 = e3;
      for (int m = 1; m < 64; m <<= 1){
        s0 += __shfl_xor(s0, m, 64); s1 += __shfl_xor(s1, m, 64);
        s2 += __shfl_xor(s2, m, 64); s3 += __shfl_xor(s3, m, 64);
      }
      sh = (h == 0) ? s0 : (h == 1) ? s1 : (h == 2) ? s2 : s3;
      int q = 0;
      for (; q + 4 <= deg; q += 4){
        int o0 = sLds[w][q],   o1 = sLds[w][q+1];
        int o2 = sLds[w][q+2], o3 = sLds[w][q+3];
        float w0 = eLds[w][h][q],   w1 = eLds[w][h][q+1];
        float w2 = eLds[w][h][q+2], w3 = eLds[w][h][q+3];
        ushort4 u0 = *(const ushort4*)(xwp + o0 + lb);
        ushort4 u1 = *(const ushort4*)(xwp + o1 + lb);
        ushort4 u2 = *(const ushort4*)(xwp + o2 + lb);
        ushort4 u3 = *(const ushort4*)(xwp + o3 + lb);
        accx += w0*b2f(u0.x) + w1*b2f(u1.x) + w2*b2f(u2.x) + w3*b2f(u3.x);
        accy += w0*b2f(u0.y) + w1*b2f(u1.y) + w2*b2f(u2.y) + w3*b2f(u3.y);
        accz += w0*b2f(u0.z) + w1*b2f(u1.z) + w2*b2f(u2.z) + w3*b2f(u3.z);
        accw += w0*b2f(u0.w) + w1*b2f(u1.w) + w2*b2f(u2.w) + w3*b2f(u3.w);
      }
      for (; q < deg; ++q){
        int o0 = sLds[w][q];
        float wh = eLds[w][h][q];
        ushort4 u = *(const ushort4*)(xwp + o0 + lb);
        accx += wh * b2f(u.x); accy += wh * b2f(u.y);
        accz += wh * b2f(u.z); accw += wh * b2f(u.w);
      }
    } else {
      float s0 = 0.f, s1 = 0.f, s2 = 0.f, s3 = 0.f;
      for (int j = lane; j < deg; j += 64){
        int s = csr_src[row0 + j];
        float4 a4 = *(const float4*)&as_[s * 4];
        s0 += __expf(lrelu(a4.x + ad4.x));
        s1 += __expf(lrelu(a4.y + ad4.y));
        s2 += __expf(lrelu(a4.z + ad4.z));
        s3 += __expf(lrelu(a4.w + ad4.w));
      }
      for (int m = 1; m < 64; m <<= 1){
        s0 += __shfl_xor(s0, m, 64); s1 += __shfl_xor(s1, m, 64);
        s2 += __shfl_xor(s2, m, 64); s3 += __shfl_xor(s3, m, 64);
      }
      sh = (h == 0) ? s0 : (h == 1) ? s1 : (h == 2) ? s2 : s3;
      for (int jb = 0; jb < deg; jb += 64){
        int jj = jb + lane;
        int soff = 0; float e0 = 0.f, e1 = 0.f, e2 = 0.f, e3 = 0.f;
        if (jj < deg){
          int sreg = csr_src[row0 + jj];
          soff = sreg << 9;
          float4 a4 = *(const float4*)&as_[sreg * 4];
          e0 = __expf(lrelu(a4.x + ad4.x));
          e1 = __expf(lrelu(a4.y + ad4.y));
          e2 = __expf(lrelu(a4.z + ad4.z));
          e3 = __expf(lrelu(a4.w + ad4.w));
        }
        sLds[w][lane] = soff;
        eLds[w][0][lane] = e0; eLds[w][1][lane] = e1;
        eLds[w][2][lane] = e2; eLds[w][3][lane] = e3;
        __builtin_amdgcn_s_waitcnt(0);
        int lim = min(64, deg - jb);
        for (int q = 0; q < lim; ++q){
          int o0 = sLds[w][q];
          float wh = eLds[w][h][q];
          ushort4 u = *(const ushort4*)(xwp + o0 + lb);
          accx += wh * b2f(u.x); accy += wh * b2f(u.y);
          accz += wh * b2f(u.z); accw += wh * b2f(u.w);
        }
      }
    }
    float invh = 1.f / (sh + 1e-16f);
    const float* bi = bias_p + inst * HF;
    float4 b4 = *(const float4*)&bi[lane * 4];
    ushort4 o;
    o.x = f2b(accx * invh + b4.x); o.y = f2b(accy * invh + b4.y);
    o.z = f2b(accz * invh + b4.z); o.w = f2b(accw * invh + b4.w);
    *(ushort4*)&outb[(size_t)inst * N_NODES * HF + (size_t)node * HF + lane * 4] = o;
  }
}

// ---------------- GEMM2 fused: 3 instances, BN+ReLU A-staging (permuted cols), LDS-staged B, normalize ----------------
__global__ __launch_bounds__(256) void k_gemm2f(const unsigned short* __restrict__ obase,
                                                const unsigned short* __restrict__ lwb,
                                                const float* __restrict__ scale,
                                                const float* __restrict__ shiftv,
                                                const float* __restrict__ linb,
                                                float* __restrict__ outp){
  __shared__ unsigned char Asm[64 * 512];   // 32KB
  __shared__ unsigned char Bsm[64 * 512];   // 32KB
  int tid = threadIdx.x;
  int m0 = blockIdx.x * 64;
  int w = tid >> 6, lane = tid & 63;
  int l15 = lane & 15, l4 = lane >> 4;

  fl4 acc[4] = {};

  for (int i = 0; i < 3; ++i){
    if (i) __syncthreads();
    const unsigned short* A = obase + (size_t)i * N_NODES * HF;
    const float* sc = scale + i * HF;
    const float* sf = shiftv + i * HF;
    #pragma unroll
    for (int k = 0; k < 8; ++k){
      int c = k * 256 + tid;
      int row = c >> 5;
      int colb = (c & 31) * 16;
      int col = colb >> 1;
      int grow = m0 + row; if (grow >= N_NODES) grow = N_NODES - 1;
      us8 u = *(const us8*)&A[(size_t)grow * HF + col];
      float4 s0 = *(const float4*)&sc[col], s1 = *(const float4*)&sc[col + 4];
      float4 f0 = *(const float4*)&sf[col], f1 = *(const float4*)&sf[col + 4];
      us8 o;
      o[0] = f2b(fmaxf(0.f, b2f(u[0]) * s0.x + f0.x));
      o[1] = f2b(fmaxf(0.f, b2f(u[1]) * s0.y + f0.y));
      o[2] = f2b(fmaxf(0.f, b2f(u[2]) * s0.z + f0.z));
      o[3] = f2b(fmaxf(0.f, b2f(u[3]) * s0.w + f0.w));
      o[4] = f2b(fmaxf(0.f, b2f(u[4]) * s1.x + f1.x));
      o[5] = f2b(fmaxf(0.f, b2f(u[5]) * s1.y + f1.y));
      o[6] = f2b(fmaxf(0.f, b2f(u[6]) * s1.z + f1.z));
      o[7] = f2b(fmaxf(0.f, b2f(u[7]) * s1.w + f1.w));
      *(us8*)(Asm + row * 512 + (colb ^ ((row & 7) << 4))) = o;
    }
    const unsigned short* B = lwb + (size_t)i * HID * HF;
    #pragma unroll
    for (int k = 0; k < 8; ++k){
      int c = k * 256 + tid;
      int row = c >> 5;
      int colb = (c & 31) * 16;
      uint4 v = *(const uint4*)((const char*)B + (size_t)row * 512 + colb);
      *(uint4*)(Bsm + row * 512 + (colb ^ ((row & 7) << 4))) = v;
    }
    __syncthreads();
    #pragma unroll
    for (int kk = 0; kk < 8; ++kk){
      int ar = w * 16 + l15;
      int ac = (kk * 64 + l4 * 16) ^ ((ar & 7) << 4);
      bh8 af = *(const bh8*)(Asm + ar * 512 + ac);
      #pragma unroll
      for (int n = 0; n < 4; ++n){
        int br = n * 16 + l15;
        int bc = (kk * 64 + l4 * 16) ^ ((br & 7) << 4);
        bh8 bfv = *(const bh8*)(Bsm + br * 512 + bc);
        acc[n] = __builtin_amdgcn_mfma_f32_16x16x32_bf16(af, bfv, acc[n], 0, 0, 0);
      }
    }
  }
  float lbs[4];
  #pragma unroll
  for (int n = 0; n < 4; ++n){
    int c = n * 16 + l15;
    lbs[n] = linb[c] + linb[64 + c] + linb[128 + c];
  }
  #pragma unroll
  for (int j = 0; j < 4; ++j){
    float v0 = acc[0][j] + lbs[0];
    float v1 = acc[1][j] + lbs[1];
    float v2 = acc[2][j] + lbs[2];
    float v3 = acc[3][j] + lbs[3];
    float ss = v0*v0 + v1*v1 + v2*v2 + v3*v3;
    #pragma unroll
    for (int mm = 1; mm < 16; mm <<= 1) ss += __shfl_xor(ss, mm, 64);
    float rn = 1.f / sqrtf(ss);
    int grow = m0 + w * 16 + l4 * 4 + j;
    if (grow < N_NODES){
      float* op = outp + (size_t)grow * HID;
      op[l15]      = v0 * rn;
      op[16 + l15] = v1 * rn;
      op[32 + l15] = v2 * rn;
      op[48 + l15] = v3 * rn;
    }
  }
}

extern "C" void kernel_launch(void* const* d_in, const int* in_sizes, int n_in,
                              void* d_out, int out_size, void* d_ws, size_t ws_size,
                              hipStream_t stream){
  const float* sppmi   = (const float*)d_in[0];
  const float* W       = (const float*)d_in[1];
  const float* att_src = (const float*)d_in[2];
  const float* att_dst = (const float*)d_in[3];
  const float* bias    = (const float*)d_in[4];
  const float* bn_g    = (const float*)d_in[5];
  const float* bn_b    = (const float*)d_in[6];
  const float* bn_m    = (const float*)d_in[7];
  const float* bn_v    = (const float*)d_in[8];
  const float* lin_W   = (const float*)d_in[9];
  const float* lin_b   = (const float*)d_in[10];
  const int*   ei      = (const int*)d_in[11];

  char* ws = (char*)d_ws;
  size_t off = 0;
  auto alloc = [&](size_t bytes)->char*{ char* p = ws + off; off += (bytes + 255) & ~(size_t)255; return p; };
  unsigned short* wb   = (unsigned short*)alloc((size_t)3 * HF * IN_F * 2);
  unsigned short* lwb  = (unsigned short*)alloc((size_t)3 * HID * HF * 2);
  float* scale  = (float*)alloc((size_t)3 * HF * 4);
  float* shiftv = (float*)alloc((size_t)3 * HF * 4);
  float* bias_p = (float*)alloc((size_t)3 * HF * 4);
  unsigned short* xwb  = (unsigned short*)alloc((size_t)3 * N_NODES * HF * 2);  // bf16, permuted cols
  unsigned short* outb = (unsigned short*)alloc((size_t)3 * N_NODES * HF * 2);  // bf16, permuted cols
  float* as3    = (float*)alloc((size_t)3 * N_NODES * 4 * 4);
  float* ad3    = (float*)alloc((size_t)3 * N_NODES * 4 * 4);
  int* counts   = (int*)alloc((size_t)N_NODES * 4);
  int* row_ptr  = (int*)alloc((size_t)(N_NODES + 4) * 4);
  int* cursor   = (int*)alloc((size_t)N_NODES * 4);
  int* csr      = (int*)alloc((size_t)ET * 4);
  int* bsums    = (int*)alloc((size_t)NSCAN_BLK * 4);

  hipMemsetAsync(counts, 0, (size_t)N_NODES * 4, stream);

  k_prep<<<150, 256, 0, stream>>>(W, wb, lin_W, lwb, bn_g, bn_b, bn_m, bn_v, bias,
                                  scale, shiftv, bias_p);

  k_hist<<<(ET + 255) / 256, 256, 0, stream>>>(ei, counts);
  k_bsum<<<NSCAN_BLK, 256, 0, stream>>>(counts, bsums);
  k_sfinal<<<NSCAN_BLK, 256, 0, stream>>>(counts, bsums, row_ptr, cursor);
  k_scatter<<<(ET + 255) / 256, 256, 0, stream>>>(ei, cursor, csr);

  k_gemm1f<<<3 * 1563, 256, 0, stream>>>(sppmi, wb, att_src, att_dst, xwb, as3, ad3);
  k_agg3<<<2048, 256, 0, stream>>>(xwb, as3, ad3, row_ptr, csr, bias_p, outb);
  k_gemm2f<<<782, 256, 0, stream>>>(outb, lwb, scale, shiftv, lin_b, (float*)d_out);
}

// Round 11
// 350.444 us; speedup vs baseline: 1.0590x; 1.0590x over previous
//
#include <hip/hip_runtime.h>
#include <hip/hip_bf16.h>

#define N_NODES 50000
#define E0      800000
#define ET      850000   // E0 + N_NODES self-loops
#define IN_F    128
#define HF      256
#define HID     64
#define NEG     0.2f
#define BN_EPSC 1e-5f
#define NSCAN_BLK 196    // ceil(50000/256)
#define G1_BLKS 4689     // 3 * 1563 gemm1 tiles
#define H_BLKS  3322     // ceil(850000/256) hist blocks

typedef __attribute__((ext_vector_type(8))) short bh8;            // 8 bf16 (4 VGPRs)
typedef __attribute__((ext_vector_type(4))) float fl4;            // 4 f32 accum
typedef __attribute__((ext_vector_type(8))) unsigned short us8;   // 8 u16

__device__ __forceinline__ float lrelu(float x){ return x > 0.f ? x : NEG * x; }
__device__ __forceinline__ unsigned short f2b(float f){
  unsigned int x = __float_as_uint(f);
  unsigned int r = x + 0x7FFF + ((x >> 16) & 1);   // RNE
  return (unsigned short)(r >> 16);
}
__device__ __forceinline__ float b2f(unsigned short u){
  return __uint_as_float((unsigned int)u << 16);
}

// permutation within each 64-col head block: col' = blk + l15*4 + n holds true col blk + n*16 + l15
__device__ __forceinline__ int perm_true(int cp){
  int blk = cp & ~63, r = cp & 63;
  return blk + (r & 3) * 16 + (r >> 2);
}

// ---------------- prep: W->bf16, linW->bf16 (K-permuted), BN scale/shift + bias (permuted) ----------------
#define NW4 (3 * HF * IN_F / 4)     // 24576
#define NL4 (3 * HID * HF / 4)      // 12288
__global__ __launch_bounds__(256) void k_prep(const float* __restrict__ W, unsigned short* __restrict__ wb,
                                              const float* __restrict__ linW, unsigned short* __restrict__ lwb,
                                              const float* __restrict__ g, const float* __restrict__ b,
                                              const float* __restrict__ m, const float* __restrict__ v,
                                              const float* __restrict__ bias,
                                              float* __restrict__ scale, float* __restrict__ shiftv,
                                              float* __restrict__ bias_p){
  int idx = blockIdx.x * 256 + threadIdx.x;
  if (idx < NW4){
    float4 x = ((const float4*)W)[idx];
    ((ushort4*)wb)[idx] = make_ushort4(f2b(x.x), f2b(x.y), f2b(x.z), f2b(x.w));
  } else if (idx < NW4 + NL4){
    int j = idx - NW4;
    int j4 = j * 4;
    int irow = j4 >> 8;             // [0, 192): inst*64+row
    int cp = j4 & 255;              // 4-aligned -> l15 = (cp&63)>>2
    int blk = cp & ~63, l15 = (cp & 63) >> 2;
    const float* src = linW + (size_t)irow * HF + blk + l15;
    ushort4 o = make_ushort4(f2b(src[0]), f2b(src[16]), f2b(src[32]), f2b(src[48]));
    ((ushort4*)lwb)[j] = o;
  } else if (idx < NW4 + NL4 + 3 * HF){
    int i = idx - NW4 - NL4;        // [0,768): inst*256 + col'
    int inst = i >> 8, cp = i & 255;
    int c = inst * HF + perm_true(cp);
    float s = g[c] * rsqrtf(v[c] + BN_EPSC);
    scale[i] = s;
    shiftv[i] = b[c] - m[c] * s;
  } else if (idx < NW4 + NL4 + 6 * HF){
    int i = idx - NW4 - NL4 - 3 * HF;
    int inst = i >> 8, cp = i & 255;
    bias_p[i] = bias[inst * HF + perm_true(cp)];
  }
}

// ---------------- CSR scan chain ----------------
__global__ __launch_bounds__(256) void k_bsum(const int* __restrict__ counts, int* __restrict__ bsums){
  int b = blockIdx.x;
  int t = threadIdx.x;
  int idx = b * 256 + t;
  int v = (idx < N_NODES) ? counts[idx] : 0;
  for (int m = 1; m < 64; m <<= 1) v += __shfl_xor(v, m, 64);
  __shared__ int ws[4];
  int lane = t & 63, w = t >> 6;
  if (lane == 0) ws[w] = v;
  __syncthreads();
  if (t == 0) bsums[b] = ws[0] + ws[1] + ws[2] + ws[3];
}

// fused: per-block redundant scan of bsums (196 ints) + per-block exclusive scan -> row_ptr/cursor
__global__ __launch_bounds__(256) void k_sfinal(const int* __restrict__ counts,
                                                const int* __restrict__ bsums,
                                                int* __restrict__ row_ptr, int* __restrict__ cursor){
  __shared__ int bex[256];
  __shared__ int ws0[4];
  __shared__ int ws[4];
  int b = blockIdx.x, t = threadIdx.x;
  int lane = t & 63, w = t >> 6;
  {
    int v = (t < NSCAN_BLK) ? bsums[t] : 0;
    int incl = v;
    for (int m = 1; m < 64; m <<= 1){ int n = __shfl_up(incl, m, 64); if (lane >= m) incl += n; }
    if (lane == 63) ws0[w] = incl;
    __syncthreads();
    if (t == 0){ int r = 0; for (int j = 0; j < 4; ++j){ int x = ws0[j]; ws0[j] = r; r += x; } }
    __syncthreads();
    int excl = incl - v + ws0[w];
    bex[t] = excl;
    if (b == 0 && t == 255) row_ptr[N_NODES] = excl + v;   // total == ET
    __syncthreads();
  }
  int idx = b * 256 + t;
  int v = (idx < N_NODES) ? counts[idx] : 0;
  int incl = v;
  for (int m = 1; m < 64; m <<= 1){ int n = __shfl_up(incl, m, 64); if (lane >= m) incl += n; }
  if (lane == 63) ws[w] = incl;
  __syncthreads();
  if (t == 0){ int r = 0; for (int j = 0; j < 4; ++j){ int x = ws[j]; ws[j] = r; r += x; } }
  __syncthreads();
  int excl = incl - v + ws[w];
  int pos = bex[b] + excl;
  if (idx < N_NODES){ row_ptr[idx] = pos; cursor[idx] = pos; }
}

__global__ void k_scatter(const int* __restrict__ ei, int* __restrict__ cursor,
                          int* __restrict__ csr_src){
  int e = blockIdx.x * 256 + threadIdx.x;
  if (e >= ET) return;
  int s, d;
  if (e < E0){ s = ei[e]; d = ei[E0 + e]; } else { s = e - E0; d = s; }
  int pos = atomicAdd(&cursor[d], 1);
  csr_src[pos] = s;
}

// ---------------- fused launch: gemm1f tiles (bx<G1_BLKS) || edge histogram (rest) ----------------
// gemm1f: M=32 tile, A+B LDS-staged, permuted bf16 write + alpha. 4 waves; wave w == head w.
__global__ __launch_bounds__(256) void k_g1h(const float* __restrict__ sppmi,
                                             const unsigned short* __restrict__ wb,
                                             const float* __restrict__ att_src,
                                             const float* __restrict__ att_dst,
                                             unsigned short* __restrict__ xwb,
                                             float* __restrict__ as3, float* __restrict__ ad3,
                                             const int* __restrict__ ei, int* __restrict__ counts){
  __shared__ unsigned char Asm[32 * 256];    // 8KB
  __shared__ unsigned char Bsm[256 * 256];   // 64KB
  int tid = threadIdx.x;
  int bx = blockIdx.x;

  if (bx >= G1_BLKS){
    // ---- histogram branch ----
    int e = (bx - G1_BLKS) * 256 + tid;
    if (e < ET){
      int d = (e < E0) ? ei[E0 + e] : (e - E0);
      atomicAdd(&counts[d], 1);
    }
    return;
  }

  int inst = bx / 1563;
  int m0 = (bx % 1563) * 32;
  const float* x = sppmi + (size_t)inst * N_NODES * IN_F;
  const unsigned short* wbv = wb + (size_t)inst * HF * IN_F;
  const float* asrc = att_src + inst * HF;
  const float* adst = att_dst + inst * HF;
  float* as_ = as3 + (size_t)inst * N_NODES * 4;
  float* ad_ = ad3 + (size_t)inst * N_NODES * 4;
  unsigned short* xw = xwb + (size_t)inst * N_NODES * HF;

  // stage A with fused f32->bf16
  #pragma unroll
  for (int k = 0; k < 4; ++k){
    int c = k * 256 + tid;
    int row = c >> 5;
    int c4 = c & 31;
    int grow = m0 + row; if (grow >= N_NODES) grow = N_NODES - 1;
    float4 v = *(const float4*)&x[(size_t)grow * IN_F + c4 * 4];
    ushort4 o = make_ushort4(f2b(v.x), f2b(v.y), f2b(v.z), f2b(v.w));
    int colb = c4 * 8;
    int addr = row * 256 + ((colb & ~15) ^ ((row & 7) << 4)) + (colb & 15);
    *(ushort4*)(Asm + addr) = o;
  }
  // stage B
  #pragma unroll
  for (int k = 0; k < 16; ++k){
    int c = k * 256 + tid;
    int row = c >> 4;
    int colb = (c & 15) * 16;
    uint4 v = *(const uint4*)((const char*)wbv + (size_t)row * 256 + colb);
    *(uint4*)(Bsm + row * 256 + (colb ^ ((row & 7) << 4))) = v;
  }
  __syncthreads();

  int w = tid >> 6, lane = tid & 63;
  int l15 = lane & 15, l4 = lane >> 4;
  fl4 acc[2][4] = {};
  #pragma unroll
  for (int kk = 0; kk < 4; ++kk){
    bh8 af[2];
    #pragma unroll
    for (int m = 0; m < 2; ++m){
      int ar = m * 16 + l15;
      int ac = (kk * 64 + l4 * 16) ^ ((ar & 7) << 4);
      af[m] = *(const bh8*)(Asm + ar * 256 + ac);
    }
    bh8 bfv[4];
    #pragma unroll
    for (int n = 0; n < 4; ++n){
      int br = w * 64 + n * 16 + l15;
      int bc = (kk * 64 + l4 * 16) ^ ((br & 7) << 4);
      bfv[n] = *(const bh8*)(Bsm + br * 256 + bc);
    }
    #pragma unroll
    for (int m = 0; m < 2; ++m)
      #pragma unroll
      for (int n = 0; n < 4; ++n)
        acc[m][n] = __builtin_amdgcn_mfma_f32_16x16x32_bf16(af[m], bfv[n], acc[m][n], 0, 0, 0);
  }

  float asv[4], adv[4];
  #pragma unroll
  for (int n = 0; n < 4; ++n){
    int c = w * 64 + n * 16 + l15;
    asv[n] = asrc[c]; adv[n] = adst[c];
  }

  #pragma unroll
  for (int m = 0; m < 2; ++m){
    #pragma unroll
    for (int j = 0; j < 4; ++j){
      int grow = m0 + m * 16 + l4 * 4 + j;
      if (grow < N_NODES){
        // permuted bf16 write: 4 contiguous cols' at w*64 + l15*4 (8B store)
        ushort4 o4 = make_ushort4(f2b(acc[m][0][j]), f2b(acc[m][1][j]),
                                  f2b(acc[m][2][j]), f2b(acc[m][3][j]));
        *(ushort4*)(xw + (size_t)grow * HF + w * 64 + l15 * 4) = o4;
      }
      float ts = acc[m][0][j]*asv[0] + acc[m][1][j]*asv[1] + acc[m][2][j]*asv[2] + acc[m][3][j]*asv[3];
      float td = acc[m][0][j]*adv[0] + acc[m][1][j]*adv[1] + acc[m][2][j]*adv[2] + acc[m][3][j]*adv[3];
      #pragma unroll
      for (int mm = 1; mm < 16; mm <<= 1){ ts += __shfl_xor(ts, mm, 64); td += __shfl_xor(td, mm, 64); }
      if (l15 == 0 && grow < N_NODES){
        as_[grow * 4 + w] = ts;
        ad_[grow * 4 + w] = td;
      }
    }
  }
}

// ---------------- aggregation (3 inst, permuted bf16 rows): direct dispatch, exp + LDS broadcast ----------------
// grid = 37500; inst = bx/12500; node = (bx%12500)*4 + wave.
__global__ __launch_bounds__(256) void k_agg3(const unsigned short* __restrict__ xwb,
                     const float* __restrict__ as3, const float* __restrict__ ad3,
                     const int* __restrict__ row_ptr, const int* __restrict__ csr_src,
                     const float* __restrict__ bias_p, unsigned short* __restrict__ outb){
  __shared__ float eLds[4][4][65];
  __shared__ int   sLds[4][64];   // byte offsets (src * 512)
  int bx = blockIdx.x;
  int inst = bx / 12500;
  int chunk = bx - inst * 12500;
  int w = threadIdx.x >> 6;
  int lane = threadIdx.x & 63;
  int node = chunk * 4 + w;
  int row0 = row_ptr[node];
  int deg = row_ptr[node + 1] - row0;
  const float* as_ = as3 + (size_t)inst * N_NODES * 4;
  const float* ad_ = ad3 + (size_t)inst * N_NODES * 4;
  float4 ad4 = *(const float4*)&ad_[node * 4];
  int h = lane >> 4;
  float accx = 0.f, accy = 0.f, accz = 0.f, accw = 0.f;
  float sh;
  const char* xwp = (const char*)(xwb + (size_t)inst * N_NODES * HF);
  int lb = lane * 8;

  if (deg <= 64){
    int soff = 0; float e0 = 0.f, e1 = 0.f, e2 = 0.f, e3 = 0.f;
    if (lane < deg){
      int sreg = csr_src[row0 + lane];
      soff = sreg << 9;   // *512B
      float4 a4 = *(const float4*)&as_[sreg * 4];
      e0 = __expf(lrelu(a4.x + ad4.x));
      e1 = __expf(lrelu(a4.y + ad4.y));
      e2 = __expf(lrelu(a4.z + ad4.z));
      e3 = __expf(lrelu(a4.w + ad4.w));
    }
    sLds[w][lane] = soff;
    eLds[w][0][lane] = e0; eLds[w][1][lane] = e1;
    eLds[w][2][lane] = e2; eLds[w][3][lane] = e3;
    float s0 = e0, s1 = e1, s2 = e2, s3 = e3;
    for (int m = 1; m < 64; m <<= 1){
      s0 += __shfl_xor(s0, m, 64); s1 += __shfl_xor(s1, m, 64);
      s2 += __shfl_xor(s2, m, 64); s3 += __shfl_xor(s3, m, 64);
    }
    sh = (h == 0) ? s0 : (h == 1) ? s1 : (h == 2) ? s2 : s3;
    int q = 0;
    for (; q + 4 <= deg; q += 4){
      int o0 = sLds[w][q],   o1 = sLds[w][q+1];
      int o2 = sLds[w][q+2], o3 = sLds[w][q+3];
      float w0 = eLds[w][h][q],   w1 = eLds[w][h][q+1];
      float w2 = eLds[w][h][q+2], w3 = eLds[w][h][q+3];
      ushort4 u0 = *(const ushort4*)(xwp + o0 + lb);
      ushort4 u1 = *(const ushort4*)(xwp + o1 + lb);
      ushort4 u2 = *(const ushort4*)(xwp + o2 + lb);
      ushort4 u3 = *(const ushort4*)(xwp + o3 + lb);
      accx += w0*b2f(u0.x) + w1*b2f(u1.x) + w2*b2f(u2.x) + w3*b2f(u3.x);
      accy += w0*b2f(u0.y) + w1*b2f(u1.y) + w2*b2f(u2.y) + w3*b2f(u3.y);
      accz += w0*b2f(u0.z) + w1*b2f(u1.z) + w2*b2f(u2.z) + w3*b2f(u3.z);
      accw += w0*b2f(u0.w) + w1*b2f(u1.w) + w2*b2f(u2.w) + w3*b2f(u3.w);
    }
    for (; q < deg; ++q){
      int o0 = sLds[w][q];
      float wh = eLds[w][h][q];
      ushort4 u = *(const ushort4*)(xwp + o0 + lb);
      accx += wh * b2f(u.x); accy += wh * b2f(u.y);
      accz += wh * b2f(u.z); accw += wh * b2f(u.w);
    }
  } else {
    float s0 = 0.f, s1 = 0.f, s2 = 0.f, s3 = 0.f;
    for (int j = lane; j < deg; j += 64){
      int s = csr_src[row0 + j];
      float4 a4 = *(const float4*)&as_[s * 4];
      s0 += __expf(lrelu(a4.x + ad4.x));
      s1 += __expf(lrelu(a4.y + ad4.y));
      s2 += __expf(lrelu(a4.z + ad4.z));
      s3 += __expf(lrelu(a4.w + ad4.w));
    }
    for (int m = 1; m < 64; m <<= 1){
      s0 += __shfl_xor(s0, m, 64); s1 += __shfl_xor(s1, m, 64);
      s2 += __shfl_xor(s2, m, 64); s3 += __shfl_xor(s3, m, 64);
    }
    sh = (h == 0) ? s0 : (h == 1) ? s1 : (h == 2) ? s2 : s3;
    for (int jb = 0; jb < deg; jb += 64){
      int jj = jb + lane;
      int soff = 0; float e0 = 0.f, e1 = 0.f, e2 = 0.f, e3 = 0.f;
      if (jj < deg){
        int sreg = csr_src[row0 + jj];
        soff = sreg << 9;
        float4 a4 = *(const float4*)&as_[sreg * 4];
        e0 = __expf(lrelu(a4.x + ad4.x));
        e1 = __expf(lrelu(a4.y + ad4.y));
        e2 = __expf(lrelu(a4.z + ad4.z));
        e3 = __expf(lrelu(a4.w + ad4.w));
      }
      sLds[w][lane] = soff;
      eLds[w][0][lane] = e0; eLds[w][1][lane] = e1;
      eLds[w][2][lane] = e2; eLds[w][3][lane] = e3;
      __builtin_amdgcn_s_waitcnt(0);
      int lim = min(64, deg - jb);
      for (int q = 0; q < lim; ++q){
        int o0 = sLds[w][q];
        float wh = eLds[w][h][q];
        ushort4 u = *(const ushort4*)(xwp + o0 + lb);
        accx += wh * b2f(u.x); accy += wh * b2f(u.y);
        accz += wh * b2f(u.z); accw += wh * b2f(u.w);
      }
    }
  }
  float invh = 1.f / (sh + 1e-16f);
  const float* bi = bias_p + inst * HF;
  float4 b4 = *(const float4*)&bi[lane * 4];
  ushort4 o;
  o.x = f2b(accx * invh + b4.x); o.y = f2b(accy * invh + b4.y);
  o.z = f2b(accz * invh + b4.z); o.w = f2b(accw * invh + b4.w);
  *(ushort4*)&outb[(size_t)inst * N_NODES * HF + (size_t)node * HF + lane * 4] = o;
}

// ---------------- GEMM2 fused: 3 instances, BN+ReLU A-staging (permuted cols), LDS-staged B, normalize ----------------
__global__ __launch_bounds__(256) void k_gemm2f(const unsigned short* __restrict__ obase,
                                                const unsigned short* __restrict__ lwb,
                                                const float* __restrict__ scale,
                                                const float* __restrict__ shiftv,
                                                const float* __restrict__ linb,
                                                float* __restrict__ outp){
  __shared__ unsigned char Asm[64 * 512];   // 32KB
  __shared__ unsigned char Bsm[64 * 512];   // 32KB
  int tid = threadIdx.x;
  int m0 = blockIdx.x * 64;
  int w = tid >> 6, lane = tid & 63;
  int l15 = lane & 15, l4 = lane >> 4;

  fl4 acc[4] = {};

  for (int i = 0; i < 3; ++i){
    if (i) __syncthreads();
    const unsigned short* A = obase + (size_t)i * N_NODES * HF;
    const float* sc = scale + i * HF;
    const float* sf = shiftv + i * HF;
    #pragma unroll
    for (int k = 0; k < 8; ++k){
      int c = k * 256 + tid;
      int row = c >> 5;
      int colb = (c & 31) * 16;
      int col = colb >> 1;
      int grow = m0 + row; if (grow >= N_NODES) grow = N_NODES - 1;
      us8 u = *(const us8*)&A[(size_t)grow * HF + col];
      float4 s0 = *(const float4*)&sc[col], s1 = *(const float4*)&sc[col + 4];
      float4 f0 = *(const float4*)&sf[col], f1 = *(const float4*)&sf[col + 4];
      us8 o;
      o[0] = f2b(fmaxf(0.f, b2f(u[0]) * s0.x + f0.x));
      o[1] = f2b(fmaxf(0.f, b2f(u[1]) * s0.y + f0.y));
      o[2] = f2b(fmaxf(0.f, b2f(u[2]) * s0.z + f0.z));
      o[3] = f2b(fmaxf(0.f, b2f(u[3]) * s0.w + f0.w));
      o[4] = f2b(fmaxf(0.f, b2f(u[4]) * s1.x + f1.x));
      o[5] = f2b(fmaxf(0.f, b2f(u[5]) * s1.y + f1.y));
      o[6] = f2b(fmaxf(0.f, b2f(u[6]) * s1.z + f1.z));
      o[7] = f2b(fmaxf(0.f, b2f(u[7]) * s1.w + f1.w));
      *(us8*)(Asm + row * 512 + (colb ^ ((row & 7) << 4))) = o;
    }
    const unsigned short* B = lwb + (size_t)i * HID * HF;
    #pragma unroll
    for (int k = 0; k < 8; ++k){
      int c = k * 256 + tid;
      int row = c >> 5;
      int colb = (c & 31) * 16;
      uint4 v = *(const uint4*)((const char*)B + (size_t)row * 512 + colb);
      *(uint4*)(Bsm + row * 512 + (colb ^ ((row & 7) << 4))) = v;
    }
    __syncthreads();
    #pragma unroll
    for (int kk = 0; kk < 8; ++kk){
      int ar = w * 16 + l15;
      int ac = (kk * 64 + l4 * 16) ^ ((ar & 7) << 4);
      bh8 af = *(const bh8*)(Asm + ar * 512 + ac);
      #pragma unroll
      for (int n = 0; n < 4; ++n){
        int br = n * 16 + l15;
        int bc = (kk * 64 + l4 * 16) ^ ((br & 7) << 4);
        bh8 bfv = *(const bh8*)(Bsm + br * 512 + bc);
        acc[n] = __builtin_amdgcn_mfma_f32_16x16x32_bf16(af, bfv, acc[n], 0, 0, 0);
      }
    }
  }
  float lbs[4];
  #pragma unroll
  for (int n = 0; n < 4; ++n){
    int c = n * 16 + l15;
    lbs[n] = linb[c] + linb[64 + c] + linb[128 + c];
  }
  #pragma unroll
  for (int j = 0; j < 4; ++j){
    float v0 = acc[0][j] + lbs[0];
    float v1 = acc[1][j] + lbs[1];
    float v2 = acc[2][j] + lbs[2];
    float v3 = acc[3][j] + lbs[3];
    float ss = v0*v0 + v1*v1 + v2*v2 + v3*v3;
    #pragma unroll
    for (int mm = 1; mm < 16; mm <<= 1) ss += __shfl_xor(ss, mm, 64);
    float rn = 1.f / sqrtf(ss);
    int grow = m0 + w * 16 + l4 * 4 + j;
    if (grow < N_NODES){
      float* op = outp + (size_t)grow * HID;
      op[l15]      = v0 * rn;
      op[16 + l15] = v1 * rn;
      op[32 + l15] = v2 * rn;
      op[48 + l15] = v3 * rn;
    }
  }
}

extern "C" void kernel_launch(void* const* d_in, const int* in_sizes, int n_in,
                              void* d_out, int out_size, void* d_ws, size_t ws_size,
                              hipStream_t stream){
  const float* sppmi   = (const float*)d_in[0];
  const float* W       = (const float*)d_in[1];
  const float* att_src = (const float*)d_in[2];
  const float* att_dst = (const float*)d_in[3];
  const float* bias    = (const float*)d_in[4];
  const float* bn_g    = (const float*)d_in[5];
  const float* bn_b    = (const float*)d_in[6];
  const float* bn_m    = (const float*)d_in[7];
  const float* bn_v    = (const float*)d_in[8];
  const float* lin_W   = (const float*)d_in[9];
  const float* lin_b   = (const float*)d_in[10];
  const int*   ei      = (const int*)d_in[11];

  char* ws = (char*)d_ws;
  size_t off = 0;
  auto alloc = [&](size_t bytes)->char*{ char* p = ws + off; off += (bytes + 255) & ~(size_t)255; return p; };
  unsigned short* wb   = (unsigned short*)alloc((size_t)3 * HF * IN_F * 2);
  unsigned short* lwb  = (unsigned short*)alloc((size_t)3 * HID * HF * 2);
  float* scale  = (float*)alloc((size_t)3 * HF * 4);
  float* shiftv = (float*)alloc((size_t)3 * HF * 4);
  float* bias_p = (float*)alloc((size_t)3 * HF * 4);
  unsigned short* xwb  = (unsigned short*)alloc((size_t)3 * N_NODES * HF * 2);  // bf16, permuted cols
  unsigned short* outb = (unsigned short*)alloc((size_t)3 * N_NODES * HF * 2);  // bf16, permuted cols
  float* as3    = (float*)alloc((size_t)3 * N_NODES * 4 * 4);
  float* ad3    = (float*)alloc((size_t)3 * N_NODES * 4 * 4);
  int* counts   = (int*)alloc((size_t)N_NODES * 4);
  int* row_ptr  = (int*)alloc((size_t)(N_NODES + 4) * 4);
  int* cursor   = (int*)alloc((size_t)N_NODES * 4);
  int* csr      = (int*)alloc((size_t)ET * 4);
  int* bsums    = (int*)alloc((size_t)NSCAN_BLK * 4);

  hipMemsetAsync(counts, 0, (size_t)N_NODES * 4, stream);

  k_prep<<<150, 256, 0, stream>>>(W, wb, lin_W, lwb, bn_g, bn_b, bn_m, bn_v, bias,
                                  scale, shiftv, bias_p);

  // gemm1f || edge histogram in one launch (independent work)
  k_g1h<<<G1_BLKS + H_BLKS, 256, 0, stream>>>(sppmi, wb, att_src, att_dst, xwb, as3, ad3,
                                              ei, counts);
  k_bsum<<<NSCAN_BLK, 256, 0, stream>>>(counts, bsums);
  k_sfinal<<<NSCAN_BLK, 256, 0, stream>>>(counts, bsums, row_ptr, cursor);
  k_scatter<<<(ET + 255) / 256, 256, 0, stream>>>(ei, cursor, csr);

  k_agg3<<<37500, 256, 0, stream>>>(xwb, as3, ad3, row_ptr, csr, bias_p, outb);
  k_gemm2f<<<782, 256, 0, stream>>>(outb, lwb, scale, shiftv, lin_b, (float*)d_out);
}